// Round 4
// baseline (74.256 us; speedup 1.0000x reference)
//
#include <hip/hip_runtime.h>

#define BSES 64
#define EDIM 128
#define HDIM 128
#define KSCALE 2.8853900817779268f  // 2*log2(e): exp(2x) = exp2(KSCALE*x)

__device__ __forceinline__ float fexp2(float x) {
#if __has_builtin(__builtin_amdgcn_exp2f)
  return __builtin_amdgcn_exp2f(x);
#else
  return exp2f(x);
#endif
}
__device__ __forceinline__ float frcp(float x) {
#if __has_builtin(__builtin_amdgcn_rcpf)
  return __builtin_amdgcn_rcpf(x);
#else
  return 1.0f / x;
#endif
}

// 4-way batched reciprocal sum: w0/x0 + w1/x1 + w2/x2 + w3/x3
// = (n01*p23 + n23*p01) * rcp(p01*p23), x_j = fma(s_j, v_j, 1).
// 13 VALU + 1 rcp per 4 elements (vs 8 VALU + 4 rcp).
__device__ __forceinline__ float g4(float s0, float s1, float s2, float s3,
                                    float w0, float w1, float w2, float w3,
                                    float4 v, float acc) {
  float x0 = fmaf(s0, v.x, 1.f);
  float x1 = fmaf(s1, v.y, 1.f);
  float x2 = fmaf(s2, v.z, 1.f);
  float x3 = fmaf(s3, v.w, 1.f);
  float p01 = x0 * x1, p23 = x2 * x3;
  float n01 = fmaf(w1, x0, w0 * x1);
  float n23 = fmaf(w3, x2, w2 * x3);
  float num = fmaf(n23, p01, n01 * p23);
  return fmaf(num, frcp(p01 * p23), acc);
}

// Fused projections. Blocks [0, nbTP): etp[n][h] = exp2((emb[n]·W2[:,h]+b2[h])*K)
// (32 rows per block). Blocks [nbTP, ...): espT[h][b] = exp2((sess[b]·W1[:,h]+b1[h])*K)
// transposed for coalesced k2 reads; plus C = sum(W3)+b3.
__global__ __launch_bounds__(256) void taa_k1(
    const float* __restrict__ sess, const float* __restrict__ W1,
    const float* __restrict__ b1, const float* __restrict__ emb,
    const float* __restrict__ W2, const float* __restrict__ b2,
    const float* __restrict__ W3, const float* __restrict__ b3,
    float* __restrict__ etp, float* __restrict__ espT,
    float* __restrict__ C_out, int N, int nbTP) {
  if ((int)blockIdx.x < nbTP) {
    __shared__ float sm[32][132];  // emb tile, padded stride
    const int nb = blockIdx.x * 32;
    for (int k = threadIdx.x; k < 32 * 32; k += 256) {
      int r = k >> 5, c4 = k & 31;
      float4 v = make_float4(0.f, 0.f, 0.f, 0.f);
      if (nb + r < N) v = ((const float4*)(emb + (size_t)(nb + r) * EDIM))[c4];
      *(float4*)&sm[r][c4 * 4] = v;
    }
    __syncthreads();
    const int h4 = (threadIdx.x & 31) * 4;
    const int rg = threadIdx.x >> 5;
    float acc[4][4];
#pragma unroll
    for (int j = 0; j < 4; ++j)
#pragma unroll
      for (int q = 0; q < 4; ++q) acc[j][q] = 0.f;
    for (int e = 0; e < EDIM; e += 4) {
      float4 w[4];
#pragma unroll
      for (int q = 0; q < 4; ++q)
        w[q] = *(const float4*)(W2 + (size_t)(e + q) * HDIM + h4);
#pragma unroll
      for (int j = 0; j < 4; ++j) {
        float4 em = *(const float4*)&sm[rg * 4 + j][e];
        acc[j][0] = fmaf(em.x, w[0].x, acc[j][0]);
        acc[j][1] = fmaf(em.x, w[0].y, acc[j][1]);
        acc[j][2] = fmaf(em.x, w[0].z, acc[j][2]);
        acc[j][3] = fmaf(em.x, w[0].w, acc[j][3]);
        acc[j][0] = fmaf(em.y, w[1].x, acc[j][0]);
        acc[j][1] = fmaf(em.y, w[1].y, acc[j][1]);
        acc[j][2] = fmaf(em.y, w[1].z, acc[j][2]);
        acc[j][3] = fmaf(em.y, w[1].w, acc[j][3]);
        acc[j][0] = fmaf(em.z, w[2].x, acc[j][0]);
        acc[j][1] = fmaf(em.z, w[2].y, acc[j][1]);
        acc[j][2] = fmaf(em.z, w[2].z, acc[j][2]);
        acc[j][3] = fmaf(em.z, w[2].w, acc[j][3]);
        acc[j][0] = fmaf(em.w, w[3].x, acc[j][0]);
        acc[j][1] = fmaf(em.w, w[3].y, acc[j][1]);
        acc[j][2] = fmaf(em.w, w[3].z, acc[j][2]);
        acc[j][3] = fmaf(em.w, w[3].w, acc[j][3]);
      }
    }
    float4 bb = *(const float4*)(b2 + h4);
#pragma unroll
    for (int j = 0; j < 4; ++j) {
      int n = nb + rg * 4 + j;
      if (n < N) {
        float4 o;
        o.x = fexp2((acc[j][0] + bb.x) * KSCALE);
        o.y = fexp2((acc[j][1] + bb.y) * KSCALE);
        o.z = fexp2((acc[j][2] + bb.z) * KSCALE);
        o.w = fexp2((acc[j][3] + bb.w) * KSCALE);
        *(float4*)(etp + (size_t)n * HDIM + h4) = o;
      }
    }
  } else {
    int t = ((int)blockIdx.x - nbTP) * 256 + threadIdx.x;
    if (t < BSES * HDIM) {
      int b = t >> 7, h = t & 127;
      const float* srow = sess + b * EDIM;
      float acc = 0.f;
#pragma unroll 4
      for (int e = 0; e < EDIM; ++e)
        acc = fmaf(srow[e], W1[e * HDIM + h], acc);
      espT[h * BSES + b] = fexp2((acc + b1[h]) * KSCALE);
    }
    if (t == 0) {
      float s = b3[0];
      for (int i = 0; i < HDIM; ++i) s += W3[i];
      *C_out = s;
    }
  }
}

// Main: lane = session b. Wave handles 4 targets. Fully unrolled over the 8
// h-chunks so the scheduler pipelines chunk c+1 loads under chunk c math.
// score[b][n] = C - 2 * sum_h w3[h] * rcp(fma(espT[h][b], etp[n][h], 1))
__global__ __launch_bounds__(256, 4) void taa_k2(
    const float* __restrict__ etp, const float* __restrict__ espT,
    const float* __restrict__ w3, const float* __restrict__ Cptr,
    float* __restrict__ out, int N) {
  const int lane = threadIdx.x & 63;
  const int wave = blockIdx.x * (blockDim.x >> 6) + (threadIdx.x >> 6);
  const int n0 = wave * 4;
  if (n0 >= N) return;
  const float* tr = etp + (size_t)n0 * HDIM;
  float aA[4] = {0.f, 0.f, 0.f, 0.f};
  float aB[4] = {0.f, 0.f, 0.f, 0.f};
#pragma unroll
  for (int c = 0; c < HDIM; c += 16) {
    float spc[16];
#pragma unroll
    for (int k = 0; k < 16; ++k) spc[k] = espT[(c + k) * BSES + lane];  // coalesced
    float wsc[16];
#pragma unroll
    for (int k = 0; k < 16; ++k) wsc[k] = w3[c + k];  // uniform -> s_load
#pragma unroll
    for (int i = 0; i < 4; ++i) {
      const float4* t4 = (const float4*)(tr + i * HDIM + c);
      float4 v0 = t4[0], v1 = t4[1], v2 = t4[2], v3 = t4[3];
      aA[i] = g4(spc[0], spc[1], spc[2], spc[3],
                 wsc[0], wsc[1], wsc[2], wsc[3], v0, aA[i]);
      aB[i] = g4(spc[4], spc[5], spc[6], spc[7],
                 wsc[4], wsc[5], wsc[6], wsc[7], v1, aB[i]);
      aA[i] = g4(spc[8], spc[9], spc[10], spc[11],
                 wsc[8], wsc[9], wsc[10], wsc[11], v2, aA[i]);
      aB[i] = g4(spc[12], spc[13], spc[14], spc[15],
                 wsc[12], wsc[13], wsc[14], wsc[15], v3, aB[i]);
    }
  }
  const float Cv = *Cptr;  // uniform -> s_load
  float4 res;
  res.x = fmaf(-2.f, aA[0] + aB[0], Cv);
  res.y = fmaf(-2.f, aA[1] + aB[1], Cv);
  res.z = fmaf(-2.f, aA[2] + aB[2], Cv);
  res.w = fmaf(-2.f, aA[3] + aB[3], Cv);
  if (n0 + 3 < N) {
    *(float4*)(out + (size_t)lane * N + n0) = res;
  } else {
    float r4[4] = {res.x, res.y, res.z, res.w};
    for (int i = 0; i < 4 && n0 + i < N; ++i) out[(size_t)lane * N + n0 + i] = r4[i];
  }
}

extern "C" void kernel_launch(void* const* d_in, const int* in_sizes, int n_in,
                              void* d_out, int out_size, void* d_ws, size_t ws_size,
                              hipStream_t stream) {
  const float* sess = (const float*)d_in[0];
  const float* emb  = (const float*)d_in[1];
  const float* W1   = (const float*)d_in[2];
  const float* b1   = (const float*)d_in[3];
  const float* W2   = (const float*)d_in[4];
  const float* b2   = (const float*)d_in[5];
  const float* W3   = (const float*)d_in[6];
  const float* b3   = (const float*)d_in[7];
  float* out = (float*)d_out;
  const int B = in_sizes[0] / EDIM;   // 64
  const int N = in_sizes[1] / EDIM;   // 20000

  float* etp  = (float*)d_ws;                     // N*128 floats
  float* espT = etp + (size_t)N * HDIM;           // 128*64 floats (transposed)
  float* Cp   = espT + (size_t)HDIM * BSES;       // 1 float

  const int nbTP = (N + 31) / 32;                 // 625
  const int nbSP = (B * HDIM + 255) / 256;        // 32
  taa_k1<<<nbTP + nbSP, 256, 0, stream>>>(sess, W1, b1, emb, W2, b2, W3, b3,
                                          etp, espT, Cp, N, nbTP);
  const int waves = (N + 3) / 4;
  taa_k2<<<(waves * 64 + 255) / 256, 256, 0, stream>>>(etp, espT, W3, Cp, out, N);
}

// Round 5
// 49.098 us; speedup vs baseline: 1.5124x; 1.5124x over previous
//
#include <hip/hip_runtime.h>

#define BSES 64
#define EDIM 128
#define HDIM 128
#define NTILE 32
#define KSCALE 2.8853900817779268f  // 2*log2(e): exp(2x) = exp2(KSCALE*x)

__device__ __forceinline__ float fexp2(float x) {
#if __has_builtin(__builtin_amdgcn_exp2f)
  return __builtin_amdgcn_exp2f(x);
#else
  return exp2f(x);
#endif
}
__device__ __forceinline__ float frcp(float x) {
#if __has_builtin(__builtin_amdgcn_rcpf)
  return __builtin_amdgcn_rcpf(x);
#else
  return 1.0f / x;
#endif
}

// 4-way batched reciprocal sum: w0/x0 + w1/x1 + w2/x2 + w3/x3,
// x_j = fma(s_j, v_j, 1). 13 VALU + 1 rcp per 4 elements.
__device__ __forceinline__ float g4(float s0, float s1, float s2, float s3,
                                    float w0, float w1, float w2, float w3,
                                    float v0, float v1, float v2, float v3,
                                    float acc) {
  float x0 = fmaf(s0, v0, 1.f);
  float x1 = fmaf(s1, v1, 1.f);
  float x2 = fmaf(s2, v2, 1.f);
  float x3 = fmaf(s3, v3, 1.f);
  float p01 = x0 * x1, p23 = x2 * x3;
  float n01 = fmaf(w1, x0, w0 * x1);
  float n23 = fmaf(w3, x2, w2 * x3);
  float num = fmaf(n23, p01, n01 * p23);
  return fmaf(num, frcp(p01 * p23), acc);
}

// esp[b][h] = exp2((sess[b]·W1[:,h] + b1[h]) * K)  (b-major, natural layout);
// also C = sum(W3) + b3.
__global__ __launch_bounds__(256) void taa_k1a(
    const float* __restrict__ sess, const float* __restrict__ W1,
    const float* __restrict__ b1, const float* __restrict__ W3,
    const float* __restrict__ b3, float* __restrict__ esp,
    float* __restrict__ C_out) {
  int t = blockIdx.x * blockDim.x + threadIdx.x;
  if (t < BSES * HDIM) {
    int b = t >> 7, h = t & 127;
    const float* srow = sess + b * EDIM;
    float acc = 0.f;
#pragma unroll 4
    for (int e = 0; e < EDIM; ++e)
      acc = fmaf(srow[e], W1[e * HDIM + h], acc);
    esp[t] = fexp2((acc + b1[h]) * KSCALE);
  }
  if (t == 0) {
    float s = b3[0];
    for (int i = 0; i < HDIM; ++i) s += W3[i];
    *C_out = s;
  }
}

// Fused: per block, one 32-target tile.
// Phase 1: emb tile -> LDS. Phase 2: 32x128 @ 128x128 GEMM (k1b inner loop),
// exp2, write TRANSPOSED to et[128][33]. Phase 3: score; lane&31 = target col
// (conflict-free LDS), wave w owns sessions w*16..+15 split 8/8 by lane-half
// via per-lane esp base (L1-hot dwordx4); g4 batched reciprocal.
// score[b][n] = C - 2 * sum_h w3[h] * rcp(fma(esp[b][h], etp[n][h], 1))
__global__ __launch_bounds__(256) void taa_fused(
    const float* __restrict__ emb, const float* __restrict__ W2,
    const float* __restrict__ b2, const float* __restrict__ esp,
    const float* __restrict__ w3, const float* __restrict__ Cptr,
    float* __restrict__ out, int N) {
  __shared__ float sm[NTILE][132];      // emb tile
  __shared__ float et[HDIM][NTILE + 1]; // exp2(tp') transposed, stride 33
  const int nb = blockIdx.x * NTILE;

  // Phase 1: stage emb tile (coalesced float4).
  for (int k = threadIdx.x; k < NTILE * 32; k += 256) {
    int r = k >> 5, c4 = k & 31;
    float4 v = make_float4(0.f, 0.f, 0.f, 0.f);
    if (nb + r < N) v = ((const float4*)(emb + (size_t)(nb + r) * EDIM))[c4];
    *(float4*)&sm[r][c4 * 4] = v;
  }
  __syncthreads();

  // Phase 2: GEMM (proven k1b inner loop) + exp2 + transposed LDS write.
  {
    const int h4 = (threadIdx.x & 31) * 4;
    const int rg = threadIdx.x >> 5;
    float acc[4][4];
#pragma unroll
    for (int j = 0; j < 4; ++j)
#pragma unroll
      for (int q = 0; q < 4; ++q) acc[j][q] = 0.f;
    for (int e = 0; e < EDIM; e += 4) {
      float4 w[4];
#pragma unroll
      for (int q = 0; q < 4; ++q)
        w[q] = *(const float4*)(W2 + (size_t)(e + q) * HDIM + h4);
#pragma unroll
      for (int j = 0; j < 4; ++j) {
        float4 em = *(const float4*)&sm[rg * 4 + j][e];
        acc[j][0] = fmaf(em.x, w[0].x, acc[j][0]);
        acc[j][1] = fmaf(em.x, w[0].y, acc[j][1]);
        acc[j][2] = fmaf(em.x, w[0].z, acc[j][2]);
        acc[j][3] = fmaf(em.x, w[0].w, acc[j][3]);
        acc[j][0] = fmaf(em.y, w[1].x, acc[j][0]);
        acc[j][1] = fmaf(em.y, w[1].y, acc[j][1]);
        acc[j][2] = fmaf(em.y, w[1].z, acc[j][2]);
        acc[j][3] = fmaf(em.y, w[1].w, acc[j][3]);
        acc[j][0] = fmaf(em.z, w[2].x, acc[j][0]);
        acc[j][1] = fmaf(em.z, w[2].y, acc[j][1]);
        acc[j][2] = fmaf(em.z, w[2].z, acc[j][2]);
        acc[j][3] = fmaf(em.z, w[2].w, acc[j][3]);
        acc[j][0] = fmaf(em.w, w[3].x, acc[j][0]);
        acc[j][1] = fmaf(em.w, w[3].y, acc[j][1]);
        acc[j][2] = fmaf(em.w, w[3].z, acc[j][2]);
        acc[j][3] = fmaf(em.w, w[3].w, acc[j][3]);
      }
    }
    float4 bb2 = *(const float4*)(b2 + h4);
#pragma unroll
    for (int j = 0; j < 4; ++j) {
      int nr = rg * 4 + j;
      et[h4 + 0][nr] = fexp2((acc[j][0] + bb2.x) * KSCALE);
      et[h4 + 1][nr] = fexp2((acc[j][1] + bb2.y) * KSCALE);
      et[h4 + 2][nr] = fexp2((acc[j][2] + bb2.z) * KSCALE);
      et[h4 + 3][nr] = fexp2((acc[j][3] + bb2.w) * KSCALE);
    }
  }
  __syncthreads();

  // Phase 3: scoring.
  const int lane = threadIdx.x & 63;
  const int wv = __builtin_amdgcn_readfirstlane((int)(threadIdx.x >> 6));
  const int nloc = lane & 31;
  const int bbase = wv * 16 + ((lane >> 5) << 3);  // 8 sessions per lane-half
  const float* espl = esp + (size_t)bbase * HDIM;  // per-lane base (2 addrs/wave)
  float sacc[8] = {0.f, 0.f, 0.f, 0.f, 0.f, 0.f, 0.f, 0.f};
  for (int hg = 0; hg < HDIM; hg += 4) {
    float v0 = et[hg + 0][nloc];
    float v1 = et[hg + 1][nloc];
    float v2 = et[hg + 2][nloc];
    float v3 = et[hg + 3][nloc];
    float w0 = w3[hg + 0], w1 = w3[hg + 1];  // uniform -> s_load
    float w2c = w3[hg + 2], w3c = w3[hg + 3];
#pragma unroll
    for (int bb = 0; bb < 8; ++bb) {
      float4 sv = *(const float4*)(espl + bb * HDIM + hg);  // L1-hot dwordx4
      sacc[bb] = g4(sv.x, sv.y, sv.z, sv.w, w0, w1, w2c, w3c,
                    v0, v1, v2, v3, sacc[bb]);
    }
  }
  const float Cv = *Cptr;  // uniform -> s_load
  const int n = nb + nloc;
  if (n < N) {
#pragma unroll
    for (int bb = 0; bb < 8; ++bb) {
      out[(size_t)(bbase + bb) * N + n] = fmaf(-2.f, sacc[bb], Cv);
    }
  }
}

extern "C" void kernel_launch(void* const* d_in, const int* in_sizes, int n_in,
                              void* d_out, int out_size, void* d_ws, size_t ws_size,
                              hipStream_t stream) {
  const float* sess = (const float*)d_in[0];
  const float* emb  = (const float*)d_in[1];
  const float* W1   = (const float*)d_in[2];
  const float* b1   = (const float*)d_in[3];
  const float* W2   = (const float*)d_in[4];
  const float* b2   = (const float*)d_in[5];
  const float* W3   = (const float*)d_in[6];
  const float* b3   = (const float*)d_in[7];
  float* out = (float*)d_out;
  const int B = in_sizes[0] / EDIM;   // 64
  const int N = in_sizes[1] / EDIM;   // 20000

  float* esp = (float*)d_ws;                      // B*128 floats
  float* Cp  = esp + (size_t)BSES * HDIM;         // 1 float

  taa_k1a<<<(B * HDIM + 255) / 256, 256, 0, stream>>>(sess, W1, b1, W3, b3, esp, Cp);
  taa_fused<<<(N + NTILE - 1) / NTILE, 256, 0, stream>>>(emb, W2, b2, esp, W3, Cp, out, N);
}

// Round 6
// 48.991 us; speedup vs baseline: 1.5157x; 1.0022x over previous
//
#include <hip/hip_runtime.h>

#define BSES 64
#define EDIM 128
#define HDIM 128
#define NTILE 32
#define TPB 512
#define KSCALE 2.8853900817779268f  // 2*log2(e): exp(2x) = exp2(KSCALE*x)

__device__ __forceinline__ float fexp2(float x) {
#if __has_builtin(__builtin_amdgcn_exp2f)
  return __builtin_amdgcn_exp2f(x);
#else
  return exp2f(x);
#endif
}
__device__ __forceinline__ float frcp(float x) {
#if __has_builtin(__builtin_amdgcn_rcpf)
  return __builtin_amdgcn_rcpf(x);
#else
  return 1.0f / x;
#endif
}

// et in-row bank-spread: h -> h + (h>>5) (h multiple of 4; injective into a
// 132-float row; spreads the 32 b128 lanes across all 32 banks).
__device__ __forceinline__ int etidx(int n, int h) {
  return n * 132 + h + (h >> 5);
}

// 4-way batched reciprocal sum: w0/x0 + w1/x1 + w2/x2 + w3/x3,
// x_j = fma(s_j, v_j, 1). 13 VALU + 1 rcp per 4 elements.
__device__ __forceinline__ float g4(float s0, float s1, float s2, float s3,
                                    float w0, float w1, float w2, float w3,
                                    float v0, float v1, float v2, float v3,
                                    float acc) {
  float x0 = fmaf(s0, v0, 1.f);
  float x1 = fmaf(s1, v1, 1.f);
  float x2 = fmaf(s2, v2, 1.f);
  float x3 = fmaf(s3, v3, 1.f);
  float p01 = x0 * x1, p23 = x2 * x3;
  float n01 = fmaf(w1, x0, w0 * x1);
  float n23 = fmaf(w3, x2, w2 * x3);
  float num = fmaf(n23, p01, n01 * p23);
  return fmaf(num, frcp(p01 * p23), acc);
}

// esp4[(h>>2)*256 + b*4 + (h&3)] = exp2((sess[b]·W1[:,h] + b1[h]) * K)
// packed so a wave (lane=b) reads 4 h-components as one coalesced dwordx4.
// Also C = sum(W3) + b3.
__global__ __launch_bounds__(256) void taa_k1a(
    const float* __restrict__ sess, const float* __restrict__ W1,
    const float* __restrict__ b1, const float* __restrict__ W3,
    const float* __restrict__ b3, float* __restrict__ esp4,
    float* __restrict__ C_out) {
  int t = blockIdx.x * blockDim.x + threadIdx.x;
  if (t < BSES * HDIM) {
    int b = t >> 7, h = t & 127;
    const float* srow = sess + b * EDIM;
    float acc = 0.f;
#pragma unroll 4
    for (int e = 0; e < EDIM; ++e)
      acc = fmaf(srow[e], W1[e * HDIM + h], acc);
    esp4[(h >> 2) * 256 + b * 4 + (h & 3)] = fexp2((acc + b1[h]) * KSCALE);
  }
  if (t == 0) {
    float s = b3[0];
    for (int i = 0; i < HDIM; ++i) s += W3[i];
    *C_out = s;
  }
}

// Fused per 32-target tile, 512 threads (8 waves).
// P1: emb tile -> LDS. P2: 32x128 @ 128x128 GEMM + exp2 -> et[n][h] (LDS,
// bank-spread rows). P3: lane = session; wave w owns targets nb+4w..+3;
// esp4 read = 1 coalesced dwordx4/iter; et reads uniform broadcast.
// score[b][n] = C - 2 * sum_h w3[h] * rcp(fma(esp[b][h], etp[n][h], 1))
__global__ __launch_bounds__(512) void taa_fused(
    const float* __restrict__ emb, const float* __restrict__ W2,
    const float* __restrict__ b2, const float* __restrict__ esp4,
    const float* __restrict__ w3, const float* __restrict__ Cptr,
    float* __restrict__ out, int N) {
  __shared__ float sm[NTILE][132];   // emb tile
  __shared__ float et[NTILE * 132];  // exp2(tp'), bank-spread rows
  const int nb = blockIdx.x * NTILE;

  // Phase 1: stage emb tile (coalesced float4, 2 per thread).
  for (int k = threadIdx.x; k < NTILE * 32; k += TPB) {
    int r = k >> 5, c4 = k & 31;
    float4 v = make_float4(0.f, 0.f, 0.f, 0.f);
    if (nb + r < N) v = ((const float4*)(emb + (size_t)(nb + r) * EDIM))[c4];
    *(float4*)&sm[r][c4 * 4] = v;
  }
  __syncthreads();

  // Phase 2: GEMM + exp2 + et write. Thread = 2 rows x 4 h.
  {
    const int h4 = (threadIdx.x & 31) * 4;
    const int rg = threadIdx.x >> 5;  // 0..15
    float acc[2][4];
#pragma unroll
    for (int j = 0; j < 2; ++j)
#pragma unroll
      for (int q = 0; q < 4; ++q) acc[j][q] = 0.f;
    for (int e = 0; e < EDIM; e += 4) {
      float4 w[4];
#pragma unroll
      for (int q = 0; q < 4; ++q)
        w[q] = *(const float4*)(W2 + (size_t)(e + q) * HDIM + h4);
#pragma unroll
      for (int j = 0; j < 2; ++j) {
        float4 em = *(const float4*)&sm[rg * 2 + j][e];
        acc[j][0] = fmaf(em.x, w[0].x, acc[j][0]);
        acc[j][1] = fmaf(em.x, w[0].y, acc[j][1]);
        acc[j][2] = fmaf(em.x, w[0].z, acc[j][2]);
        acc[j][3] = fmaf(em.x, w[0].w, acc[j][3]);
        acc[j][0] = fmaf(em.y, w[1].x, acc[j][0]);
        acc[j][1] = fmaf(em.y, w[1].y, acc[j][1]);
        acc[j][2] = fmaf(em.y, w[1].z, acc[j][2]);
        acc[j][3] = fmaf(em.y, w[1].w, acc[j][3]);
        acc[j][0] = fmaf(em.z, w[2].x, acc[j][0]);
        acc[j][1] = fmaf(em.z, w[2].y, acc[j][1]);
        acc[j][2] = fmaf(em.z, w[2].z, acc[j][2]);
        acc[j][3] = fmaf(em.z, w[2].w, acc[j][3]);
        acc[j][0] = fmaf(em.w, w[3].x, acc[j][0]);
        acc[j][1] = fmaf(em.w, w[3].y, acc[j][1]);
        acc[j][2] = fmaf(em.w, w[3].z, acc[j][2]);
        acc[j][3] = fmaf(em.w, w[3].w, acc[j][3]);
      }
    }
    float4 bb2 = *(const float4*)(b2 + h4);
#pragma unroll
    for (int j = 0; j < 2; ++j) {
      int nr = rg * 2 + j;
      float4 o;
      o.x = fexp2((acc[j][0] + bb2.x) * KSCALE);
      o.y = fexp2((acc[j][1] + bb2.y) * KSCALE);
      o.z = fexp2((acc[j][2] + bb2.z) * KSCALE);
      o.w = fexp2((acc[j][3] + bb2.w) * KSCALE);
      *(float4*)&et[etidx(nr, h4)] = o;  // conflict-free (bank-spread)
    }
  }
  __syncthreads();

  // Phase 3: scoring. lane = session; wave w -> targets nb+4w..nb+4w+3.
  const int lane = threadIdx.x & 63;
  const int wv = threadIdx.x >> 6;  // 0..7
  const int n0 = nb + wv * 4;
  float sacc0 = 0.f, sacc1 = 0.f, sacc2 = 0.f, sacc3 = 0.f;
#pragma unroll 2
  for (int hg = 0; hg < HDIM / 4; ++hg) {
    float4 sv = *(const float4*)(esp4 + (hg << 8) + (lane << 2));  // coalesced
    float w0 = w3[hg * 4 + 0], w1 = w3[hg * 4 + 1];  // uniform -> s_load
    float w2c = w3[hg * 4 + 2], w3c = w3[hg * 4 + 3];
    float4 v0 = *(const float4*)&et[etidx(wv * 4 + 0, hg * 4)];  // broadcast
    float4 v1 = *(const float4*)&et[etidx(wv * 4 + 1, hg * 4)];
    float4 v2 = *(const float4*)&et[etidx(wv * 4 + 2, hg * 4)];
    float4 v3 = *(const float4*)&et[etidx(wv * 4 + 3, hg * 4)];
    sacc0 = g4(sv.x, sv.y, sv.z, sv.w, w0, w1, w2c, w3c,
               v0.x, v0.y, v0.z, v0.w, sacc0);
    sacc1 = g4(sv.x, sv.y, sv.z, sv.w, w0, w1, w2c, w3c,
               v1.x, v1.y, v1.z, v1.w, sacc1);
    sacc2 = g4(sv.x, sv.y, sv.z, sv.w, w0, w1, w2c, w3c,
               v2.x, v2.y, v2.z, v2.w, sacc2);
    sacc3 = g4(sv.x, sv.y, sv.z, sv.w, w0, w1, w2c, w3c,
               v3.x, v3.y, v3.z, v3.w, sacc3);
  }
  const float Cv = *Cptr;  // uniform -> s_load
  float4 res;
  res.x = fmaf(-2.f, sacc0, Cv);
  res.y = fmaf(-2.f, sacc1, Cv);
  res.z = fmaf(-2.f, sacc2, Cv);
  res.w = fmaf(-2.f, sacc3, Cv);
  if (n0 + 3 < N) {
    *(float4*)(out + (size_t)lane * N + n0) = res;
  } else {
    float r4[4] = {res.x, res.y, res.z, res.w};
    for (int i = 0; i < 4 && n0 + i < N; ++i) out[(size_t)lane * N + n0 + i] = r4[i];
  }
}

extern "C" void kernel_launch(void* const* d_in, const int* in_sizes, int n_in,
                              void* d_out, int out_size, void* d_ws, size_t ws_size,
                              hipStream_t stream) {
  const float* sess = (const float*)d_in[0];
  const float* emb  = (const float*)d_in[1];
  const float* W1   = (const float*)d_in[2];
  const float* b1   = (const float*)d_in[3];
  const float* W2   = (const float*)d_in[4];
  const float* b2   = (const float*)d_in[5];
  const float* W3   = (const float*)d_in[6];
  const float* b3   = (const float*)d_in[7];
  float* out = (float*)d_out;
  const int B = in_sizes[0] / EDIM;   // 64
  const int N = in_sizes[1] / EDIM;   // 20000

  float* esp4 = (float*)d_ws;                     // B*128 floats (packed)
  float* Cp   = esp4 + (size_t)BSES * HDIM;       // 1 float

  taa_k1a<<<(B * HDIM + 255) / 256, 256, 0, stream>>>(sess, W1, b1, W3, b3, esp4, Cp);
  taa_fused<<<(N + NTILE - 1) / NTILE, TPB, 0, stream>>>(emb, W2, b2, esp4, W3, Cp, out, N);
}